// Round 12
// baseline (330.712 us; speedup 1.0000x reference)
//
#include <hip/hip_runtime.h>
#include <cstdint>
#include <cstddef>

typedef float f4 __attribute__((ext_vector_type(4)));
typedef short bf16x8 __attribute__((ext_vector_type(8)));
typedef unsigned int u32;
typedef u32 u32x4 __attribute__((ext_vector_type(4)));

#define KCORES 12
#define DCAT   8192
#define RR     256

// workspace layout (bytes)
#define WS_LOGZ  0
#define WS_NORM  256
#define WS_TABLE 16384   // bf16 transposed table: 12*8192*256*2 = 50.3 MB (ws proven >100 MB)

__device__ __forceinline__ float softplus_f(float x) {
    // matches jax.nn.softplus = max(x,0) + log1p(exp(-|x|))
    return fmaxf(x, 0.0f) + log1pf(expf(-fabsf(x)));
}

__device__ __forceinline__ u32 cvt_pk_bf16(float lo, float hi) {
    u32 r;
    asm("v_cvt_pk_bf16_f32 %0, %1, %2" : "=v"(r) : "v"(lo), "v"(hi));
    return r;  // [bf16(lo) | bf16(hi)<<16], RNE
}

// ---------------------------------------------------------------------------
// Build bf16 transposed table MT[k][d] = softplus(lc[k][d])^T + per-core norm
// sums. 16 matrices/block staged in LDS; grid = 12*8192/16 = 6144 blocks
// (full occupancy). Phase 1: coalesced f32 read + softplus + norm partials.
// Phase 2: transposed read from LDS, packed bf16 coalesced write.
// ---------------------------------------------------------------------------
__global__ __launch_bounds__(256)
void sp_norm_mt(const float* __restrict__ lc, unsigned short* __restrict__ table,
                float* __restrict__ norm) {
    __shared__ float sm[16 * 256];
    __shared__ f4 red[4][64];
    int blk = blockIdx.x;
    int t = threadIdx.x;
    int w = t >> 6, lane = t & 63;
    int k = blk >> 9;                       // 512 blocks per core (8192/16)
    const f4* in4 = (const f4*)lc + (size_t)blk * 1024;
    f4* sm4 = (f4*)sm;
    f4 acc = {0.f, 0.f, 0.f, 0.f};
    #pragma unroll
    for (int it = 0; it < 4; ++it) {        // 4*1024 floats = 16 matrices
        f4 v = in4[it * 256 + t];
        v[0] = softplus_f(v[0]); v[1] = softplus_f(v[1]);
        v[2] = softplus_f(v[2]); v[3] = softplus_f(v[3]);
        sm4[it * 256 + t] = v;
        acc += v;                            // same matrix-pos (lane*4) every it
    }
    red[w][lane] = acc;
    __syncthreads();                         // also fences sm for phase 2
    if (w == 0) {
        f4 s = red[0][lane] + red[1][lane] + red[2][lane] + red[3][lane];
        float* nk = norm + k * RR + lane * 4;
        atomicAdd(nk + 0, s[0]); atomicAdd(nk + 1, s[1]);
        atomicAdd(nk + 2, s[2]); atomicAdd(nk + 3, s[3]);
    }
    // phase 2: MT[i][j] = M[j][i], 8 bf16 (16 B) per thread per iter
    #pragma unroll
    for (int it2 = 0; it2 < 2; ++it2) {
        int e  = it2 * 2048 + t * 8;         // short index within 16-matrix chunk
        int mo = e >> 8, p = e & 255;
        int i  = p >> 4, j0 = p & 15;        // j0 in {0,8}
        const float* base = sm + mo * 256 + j0 * 16 + i;
        float v0 = base[0],   v1 = base[16],  v2 = base[32],  v3 = base[48];
        float v4 = base[64],  v5 = base[80],  v6 = base[96],  v7 = base[112];
        u32x4 wv;
        wv.x = cvt_pk_bf16(v0, v1); wv.y = cvt_pk_bf16(v2, v3);
        wv.z = cvt_pk_bf16(v4, v5); wv.w = cvt_pk_bf16(v6, v7);
        *(u32x4*)(table + (size_t)blk * 4096 + e) = wv;
    }
}

// ---------------------------------------------------------------------------
// Scale-tracked chain of the 12 norm matrices -> finite logZ in f32.
// ---------------------------------------------------------------------------
__global__ __launch_bounds__(256)
void chain_kernel(const float* __restrict__ norm, float* __restrict__ logZ) {
    __shared__ float A[16][17];
    __shared__ float Bm[16][17];
    __shared__ float red[256];
    int t = threadIdx.x;
    int i = t >> 4, j = t & 15;
    float logscale = 0.f;
    A[i][j] = norm[i * 16 + j];
    __syncthreads();
    for (int k = 1; k < KCORES; ++k) {
        Bm[i][j] = norm[k * RR + i * 16 + j];
        __syncthreads();
        float s = 0.f;
        #pragma unroll
        for (int r = 0; r < 16; ++r) s += A[i][r] * Bm[r][j];
        red[t] = s;
        __syncthreads();
        #pragma unroll
        for (int off = 128; off >= 1; off >>= 1) {
            if (t < off) red[t] = fmaxf(red[t], red[t + off]);
            __syncthreads();
        }
        float mx = red[0];
        A[i][j] = s / mx;
        if (t == 0) logscale += logf(mx);
        __syncthreads();
    }
    if (t == 0) {
        float tr = 0.f;
        #pragma unroll
        for (int r = 0; r < 16; ++r) tr += A[r][r];
        *logZ = logf(tr) + logscale;
    }
}

// ---------------------------------------------------------------------------
// MFMA chain: one sample per wave, no LDS. S_k = M_k^T @ S_{k-1} (S = P^T).
// A-operand = MT row-segments (16 B/lane, lanes 0-31; kk>=16 zero-padded).
// D lane-layout (col=lane&15,row=4g+reg; m89) -> next B via 2 cvt_pk + 4 shfl.
// Chain starts from B = I so step 0 yields S_0 = M_0^T. trace(S)=trace(P).
// ---------------------------------------------------------------------------
__global__ __launch_bounds__(256)
void trip_mfma(const int* __restrict__ index, const unsigned short* __restrict__ table,
               const float* __restrict__ logZ, float* __restrict__ out, int B) {
    int w = threadIdx.x >> 6, lane = threadIdx.x & 63;
    int b = blockIdx.x * 4 + w;
    bool live = (b < B);
    int g = lane >> 4, c = lane & 15;

    int myidx = 0;
    if (live && lane < KCORES) myidx = index[(size_t)b * KCORES + lane];

    // prefetch all 12 A-fragments: lane l<32 reads MT[c][8g..8g+7] (16 B)
    u32x4 afr[KCORES];
    #pragma unroll
    for (int k = 0; k < KCORES; ++k) {
        int d = __builtin_amdgcn_readlane(myidx, k);
        u32x4 a = {0u, 0u, 0u, 0u};
        if (lane < 32) {
            const u32x4* src = (const u32x4*)(table + (((size_t)k * DCAT + d) << 8));
            a = src[(c << 1) | g];          // byte offset c*32 + g*16
        }
        afr[k] = a;
    }

    // initial B = identity: B[8g+j][c] = (8g+j==c)
    u32 bw0 = 0, bw1 = 0, bw2 = 0, bw3 = 0;
    if ((c >> 3) == g) {
        int j = c - 8 * g;                   // 0..7
        u32 val = 0x3F80u << (16 * (j & 1)); // bf16 1.0
        if ((j >> 1) == 0) bw0 = val; else if ((j >> 1) == 1) bw1 = val;
        else if ((j >> 1) == 2) bw2 = val; else bw3 = val;
    }

    f4 acc = {0.f, 0.f, 0.f, 0.f};
    #pragma unroll
    for (int k = 0; k < KCORES; ++k) {
        u32x4 bv = {bw0, bw1, bw2, bw3};
        bf16x8 af = __builtin_bit_cast(bf16x8, afr[k]);
        bf16x8 bf = __builtin_bit_cast(bf16x8, bv);
        f4 z = {0.f, 0.f, 0.f, 0.f};
        acc = __builtin_amdgcn_mfma_f32_16x16x32_bf16(af, bf, z, 0, 0, 0);
        if (k < KCORES - 1) {
            // lane holds S[4g+r][c]; next B needs S[8g'+j][c'] from lanes
            // (2g')*16+c' and +16 (g'>=2 wraps -> garbage x A=0 -> harmless)
            u32 p0 = cvt_pk_bf16(acc[0], acc[1]);   // rows 4g, 4g+1
            u32 p1 = cvt_pk_bf16(acc[2], acc[3]);   // rows 4g+2, 4g+3
            int s0 = (g << 5) | c;
            int s1 = s0 + 16;
            bw0 = (u32)__shfl((int)p0, s0);
            bw1 = (u32)__shfl((int)p1, s0);
            bw2 = (u32)__shfl((int)p0, s1);
            bw3 = (u32)__shfl((int)p1, s1);
        }
    }

    // trace: lane holds S[4g+r][c]; diagonal when 4g+r == c
    float contrib = 0.f;
    if ((c >> 2) == g) contrib = acc[c & 3];
    #pragma unroll
    for (int off = 32; off >= 1; off >>= 1) contrib += __shfl_xor(contrib, off);
    if (live && lane == 0) out[b] = logf(contrib) - *logZ;
}

// ---------------------------------------------------------------------------
extern "C" void kernel_launch(void* const* d_in, const int* in_sizes, int n_in,
                              void* d_out, int out_size, void* d_ws, size_t ws_size,
                              hipStream_t stream) {
    const int*   idx = (const int*)d_in[0];
    const float* lc  = (const float*)d_in[1];
    float* out = (float*)d_out;
    char*  ws  = (char*)d_ws;
    float* logZ = (float*)(ws + WS_LOGZ);
    float* norm = (float*)(ws + WS_NORM);
    unsigned short* table = (unsigned short*)(ws + WS_TABLE);

    int B = in_sizes[0] / KCORES;
    int nblk = (B + 3) / 4;

    hipMemsetAsync(norm, 0, KCORES * RR * sizeof(float), stream);
    sp_norm_mt<<<KCORES * DCAT / 16, 256, 0, stream>>>(lc, table, norm);
    chain_kernel<<<1, 256, 0, stream>>>(norm, logZ);
    trip_mfma<<<nblk, 256, 0, stream>>>(idx, table, logZ, out, B);
}